// Round 17
// baseline (276.367 us; speedup 1.0000x reference)
//
#include <hip/hip_runtime.h>
#include <hip/hip_bf16.h>
#include <hip/hip_fp16.h>
#include <math.h>

// Problem constants
#define BATCH 32
#define CH_IN 3
#define CH_OUT 8
#define IMG 512
#define KSZ 7
#define CONV_OUT 506          // 512 - 6
#define KPTS 16
#define TILES_PER_B 64        // 32 row-stripes x 2 col-halves

// Conv MFMA geometry (per tile: 23 rows x 264 f16 px x 3 ch = 36.4 KB)
#define SROWS 23
#define ROW_U4 33             // 16B chunks per row
#define ROW_BYTES 528
#define SMEM_DW (CH_IN * SROWS * (ROW_BYTES / 4))   // 9108 dwords = 36.4 KB
#define NCHUNK (CH_IN * SROWS * ROW_U4)             // 2277

// Sampler: batches per block (4 block-groups x 8 = 32)
#define BPB 8

typedef _Float16 half8_t __attribute__((ext_vector_type(8)));
typedef float f32x4_t __attribute__((ext_vector_type(4)));

__device__ __forceinline__ unsigned short f2h_bits(float f) {
    _Float16 h = (_Float16)f;
    unsigned short u;
    __builtin_memcpy(&u, &h, 2);
    return u;
}
__device__ __forceinline__ float h2f_bits(unsigned short u) {
    _Float16 h;
    __builtin_memcpy(&h, &u, 2);
    return (float)h;
}
__device__ __forceinline__ unsigned int pk2(float a, float b) {
    return (unsigned int)f2h_bits(a) | ((unsigned int)f2h_bits(b) << 16);
}
__device__ __forceinline__ double ctrl_lin(int i) { return -1.0 + (2.0 / 3.0) * i; }

// ---------------------------------------------------------------------------
// Mega conv kernel: afrag built cooperatively in LDS, conv 7x7 + bias + relu
// + masked spatial sum via MFMA 16x16x32 f16, partial write, and the LAST
// block (device atomic ticket) runs the pooled-mean + FC + TPS LU solve.
// FUSED=true also emits the owned f16-image region for the sampler.
// ---------------------------------------------------------------------------
template <bool FUSED>
__global__ __launch_bounds__(256)
void conv_mega_kernel(const float* __restrict__ x, unsigned short* __restrict__ xh,
                      const float* __restrict__ conv_w, const float* __restrict__ conv_b,
                      const float* __restrict__ fc_w, const float* __restrict__ fc_b,
                      float* __restrict__ partial, float* __restrict__ Wf,
                      unsigned int* __restrict__ counter) {
    __shared__ __attribute__((aligned(16))) unsigned int smem[SMEM_DW];
    __shared__ uint4 afrag_s[6 * 64];          // 6 KB
    __shared__ float red[4][8];
    __shared__ int lastflag;
    __shared__ int piv_idx;

    int blk = blockIdx.x;
    int b = blk >> 6;
    int rem0 = blk & 63;
    int stripe = rem0 >> 1;
    int half = rem0 & 1;
    int ybase = stripe * 16;
    int x0 = half * 256;
    int tid = threadIdx.x;

    // ---- cooperative A-fragment build (parallel, L2-hot conv_w) ----
    for (int idx = tid; idx < 6 * 64; idx += 256) {
        int s = idx >> 6, l = idx & 63;
        int m = l & 15;
        int dlt = m >> 3, o = m & 7;
        int oct = s * 4 + (l >> 4);
        int c = oct >> 3, ky = oct & 7;
        unsigned short h[8];
        #pragma unroll
        for (int j = 0; j < 8; ++j) {
            int kx = j - dlt;
            float v = 0.f;
            if (ky < KSZ && kx >= 0 && kx < KSZ)
                v = conv_w[((o * CH_IN + c) * KSZ + ky) * KSZ + kx];
            h[j] = f2h_bits(v);
        }
        uint4 outv;
        __builtin_memcpy(&outv, h, 16);
        afrag_s[idx] = outv;
    }

    // ---- staging: f32 -> f16 pack -> LDS (+ owned xh region) ----
    {
        const float* xb = x + (size_t)b * CH_IN * IMG * IMG;
        unsigned short* xhb = xh + (size_t)b * CH_IN * IMG * IMG;
        for (int idx4 = tid; idx4 < NCHUNK; idx4 += 256) {
            int c = idx4 / (SROWS * ROW_U4);
            int rem = idx4 - c * (SROWS * ROW_U4);
            int r = rem / ROW_U4;
            int u4 = rem - r * ROW_U4;
            int grow = ybase + r;
            int gcol = x0 + (u4 << 3);
            uint4 v = make_uint4(0u, 0u, 0u, 0u);
            if (grow < IMG && gcol < IMG) {   // 8px chunks are fully in or out
                const float* rp = xb + ((size_t)c * IMG + grow) * IMG + gcol;
                float4 f0 = *(const float4*)rp;
                float4 f1 = *(const float4*)(rp + 4);
                v.x = pk2(f0.x, f0.y);
                v.y = pk2(f0.z, f0.w);
                v.z = pk2(f1.x, f1.y);
                v.w = pk2(f1.z, f1.w);
            }
            *(uint4*)((char*)smem + (c * SROWS + r) * ROW_BYTES + (u4 << 4)) = v;
            if (FUSED && r < 16 && u4 < 32)   // owner region: written exactly once
                *(uint4*)(xhb + ((size_t)c * IMG + grow) * IMG + gcol) = v;
        }
    }
    __syncthreads();

    int l = tid & 63, w = tid >> 6;
    int n = l & 15, g = l >> 4;

    uint4 at[6];
    #pragma unroll
    for (int s = 0; s < 6; ++s) at[s] = afrag_s[s * 64 + l];

    int rowb[6];
    #pragma unroll
    for (int s = 0; s < 6; ++s) {
        int oct = s * 4 + g;
        int c = oct >> 3, ky = oct & 7;
        rowb[s] = (c * SROWS + n + ky) * ROW_BYTES + w * 64;
    }

    float bias_[4];
    {
        int ob = (g & 1) * 4;
        #pragma unroll
        for (int r2 = 0; r2 < 4; ++r2) bias_[r2] = conv_b[ob + r2];
    }
    bool rowok = (ybase + n) < CONV_OUT;
    int dlt = g >> 1;
    float sums[4] = {0.f, 0.f, 0.f, 0.f};
    const char* sb = (const char*)smem;

    #pragma unroll
    for (int cc = 0; cc < 2; ++cc) {          // two 128-col chunks, same registers
        int off = cc * 256;
        #pragma unroll
        for (int u = 0; u < 4; ++u) {
            f32x4_t acc[4];
            #pragma unroll
            for (int d = 0; d < 4; ++d) acc[d] = (f32x4_t){0.f, 0.f, 0.f, 0.f};

            #pragma unroll
            for (int s = 0; s < 6; ++s) {
                uint4 lo = *(const uint4*)(sb + rowb[s] + off + (u << 4));
                uint4 hi = *(const uint4*)(sb + rowb[s] + off + (u << 4) + 16);
                unsigned int eu[8] = {lo.x, lo.y, lo.z, lo.w, hi.x, hi.y, hi.z, hi.w};
                half8_t a;
                __builtin_memcpy(&a, &at[s], 16);
                #pragma unroll
                for (int d = 0; d < 4; ++d) {
                    uint4 bu = make_uint4(eu[d], eu[d + 1], eu[d + 2], eu[d + 3]);
                    half8_t bf;
                    __builtin_memcpy(&bf, &bu, 16);
                    acc[d] = __builtin_amdgcn_mfma_f32_16x16x32_f16(a, bf, acc[d], 0, 0, 0);
                }
            }

            #pragma unroll
            for (int d = 0; d < 4; ++d) {
                int col = x0 + cc * 128 + 32 * w + 8 * u + 2 * d + dlt;
                bool colok = col < CONV_OUT;
                #pragma unroll
                for (int r2 = 0; r2 < 4; ++r2) {
                    float v = acc[d][r2] + bias_[r2];
                    v = v > 0.f ? v : 0.f;
                    sums[r2] += (rowok && colok) ? v : 0.f;
                }
            }
        }
    }

    #pragma unroll
    for (int r2 = 0; r2 < 4; ++r2) {
        sums[r2] += __shfl_xor(sums[r2], 1, 64);
        sums[r2] += __shfl_xor(sums[r2], 2, 64);
        sums[r2] += __shfl_xor(sums[r2], 4, 64);
        sums[r2] += __shfl_xor(sums[r2], 8, 64);
        sums[r2] += __shfl_xor(sums[r2], 32, 64);
    }
    if (l == 0) {
        #pragma unroll
        for (int r2 = 0; r2 < 4; ++r2) red[w][r2] = sums[r2];
    }
    if (l == 16) {
        #pragma unroll
        for (int r2 = 0; r2 < 4; ++r2) red[w][4 + r2] = sums[r2];
    }
    __syncthreads();
    if (tid < CH_OUT) {
        float s = red[0][tid] + red[1][tid] + red[2][tid] + red[3][tid];
        partial[tid * (BATCH * TILES_PER_B) + b * TILES_PER_B + stripe * 2 + half] = s;
    }

    // ---- last-block ticket: the final block runs the solve ----
    __threadfence();                           // release partial stores
    __syncthreads();
    if (tid == 0) {
        unsigned int done = atomicAdd(counter, 1u);
        lastflag = (done == gridDim.x - 1) ? 1 : 0;
    }
    __syncthreads();
    if (!lastflag) return;
    __threadfence();                           // acquire all partials

    // ---- solve (overlaid on dead staging LDS; barriers by all 256 threads) --
    double* L   = (double*)smem;               // 19*19
    double* Ys  = L + 19 * 19;                 // 19*64
    double* piv = Ys + 19 * 64;                // 19
    float* pooledS = (float*)(piv + 19);       // 32*8
    int t = tid;

    if (t < BATCH * CH_OUT) {
        int bb = t >> 3, o = t & 7;
        const float4* pp = (const float4*)(partial + o * (BATCH * TILES_PER_B) + bb * TILES_PER_B);
        double a0 = 0.0, a1 = 0.0, a2 = 0.0, a3 = 0.0;
        #pragma unroll
        for (int gq = 0; gq < TILES_PER_B / 4; ++gq) {
            float4 v = pp[gq];
            a0 += (double)v.x; a1 += (double)v.y;
            a2 += (double)v.z; a3 += (double)v.w;
        }
        pooledS[bb * CH_OUT + o] =
            (float)(((a0 + a1) + (a2 + a3)) / ((double)CONV_OUT * (double)CONV_OUT));
    }
    __syncthreads();

    if (t < 64) {
        int bb = t >> 1, c = t & 1;
        for (int k = 0; k < KPTS; ++k) {
            int j = k * 2 + c;
            double s = (double)fc_b[j];
            for (int o = 0; o < CH_OUT; ++o)
                s += (double)pooledS[bb * CH_OUT + o] * (double)fc_w[j * CH_OUT + o];
            Ys[k * 64 + t] = s;
        }
        for (int k = KPTS; k < 19; ++k) Ys[k * 64 + t] = 0.0;
    }

    for (int p = t; p < 19 * 19; p += 256) {
        int r = p / 19, cc = p % 19;
        double v;
        if (r < KPTS && cc < KPTS) {
            double dx = ctrl_lin(r & 3) - ctrl_lin(cc & 3);
            double dy = ctrl_lin(r >> 2) - ctrl_lin(cc >> 2);
            double d2 = dx * dx + dy * dy;
            v = d2 * log(d2 + 1e-6);
        } else if (r < KPTS) {
            v = (cc == KPTS) ? 1.0 : (cc == KPTS + 1 ? ctrl_lin(r & 3) : ctrl_lin(r >> 2));
        } else if (cc < KPTS) {
            v = (r == KPTS) ? 1.0 : (r == KPTS + 1 ? ctrl_lin(cc & 3) : ctrl_lin(cc >> 2));
        } else v = 0.0;
        L[r * 19 + cc] = v;
    }
    __syncthreads();

    for (int k = 0; k < 19; ++k) {
        if (t == 0) {
            int pi = k; double mx = fabs(L[k * 19 + k]);
            for (int i = k + 1; i < 19; ++i) {
                double a = fabs(L[i * 19 + k]);
                if (a > mx) { mx = a; pi = i; }
            }
            piv_idx = pi;
        }
        __syncthreads();
        int pi = piv_idx;
        if (pi != k) {
            if (t < 19) { double tmp = L[k * 19 + t]; L[k * 19 + t] = L[pi * 19 + t]; L[pi * 19 + t] = tmp; }
            if (t < 64) { double tmp = Ys[k * 64 + t]; Ys[k * 64 + t] = Ys[pi * 64 + t]; Ys[pi * 64 + t] = tmp; }
        }
        __syncthreads();
        if (t > k && t < 19) piv[t] = L[t * 19 + k] / L[k * 19 + k];
        __syncthreads();
        if (t > k && t < 19) {
            double lkj = L[k * 19 + t];
            for (int i = k + 1; i < 19; ++i) L[i * 19 + t] -= piv[i] * lkj;
        }
        if (t < 64) {
            double ykt = Ys[k * 64 + t];
            for (int i = k + 1; i < 19; ++i) Ys[i * 64 + t] -= piv[i] * ykt;
        }
        __syncthreads();
    }

    if (t < 64) {
        for (int k = 18; k >= 0; --k) {
            double s = Ys[k * 64 + t];
            for (int j = k + 1; j < 19; ++j) s -= L[k * 19 + j] * Ys[j * 64 + t];
            Ys[k * 64 + t] = s / L[k * 19 + k];
        }
        int bb = t >> 1, c = t & 1;
        for (int k = 0; k < 19; ++k)
            Wf[(bb * 19 + k) * 2 + c] = (float)Ys[k * 64 + t];
    }
}

// ---------------------------------------------------------------------------
// Kernel 3: fused TPS grid + bilinear sample, batch-amortized basis.
// ---------------------------------------------------------------------------
template <bool H16>
__global__ __launch_bounds__(256)
void tps_sample_kernel(const float* __restrict__ x, const unsigned short* __restrict__ xh,
                       const float* __restrict__ Wf, float* __restrict__ out) {
    int blk = blockIdx.x;
    int bgrp = blk >> 10;
    int pix = ((blk & 1023) << 8) | threadIdx.x;
    int i = pix >> 9, j = pix & 511;

    float gx = -1.f + (2.f / 511.f) * (float)j;
    float gy = -1.f + (2.f / 511.f) * (float)i;

    float U[KPTS];
    #pragma unroll
    for (int k = 0; k < KPTS; ++k) {
        float sx = -1.f + (2.f / 3.f) * (float)(k & 3);
        float sy = -1.f + (2.f / 3.f) * (float)(k >> 2);
        float dx = gx - sx, dy = gy - sy;
        float d2 = dx * dx + dy * dy;
        U[k] = d2 * (0.69314718055994531f * __log2f(d2 + 1e-6f));
    }

    for (int b = bgrp * BPB; b < bgrp * BPB + BPB; ++b) {
        const float* Wb = Wf + b * 38;

        float mx = Wb[32] + gx * Wb[34] + gy * Wb[36];
        float my = Wb[33] + gx * Wb[35] + gy * Wb[37];
        #pragma unroll
        for (int k = 0; k < KPTS; ++k) {
            mx += U[k] * Wb[2 * k];
            my += U[k] * Wb[2 * k + 1];
        }

        float ix = (mx + 1.f) * 256.f - 0.5f;
        float iy = (my + 1.f) * 256.f - 0.5f;
        float x0f = floorf(ix), y0f = floorf(iy);
        int x0 = (int)x0f, y0 = (int)y0f;
        int x1 = x0 + 1, y1 = y0 + 1;
        float wx1 = ix - x0f, wy1 = iy - y0f;
        float wx0 = 1.f - wx1, wy0 = 1.f - wy1;

        bool vx0 = (x0 >= 0) & (x0 < IMG), vx1 = (x1 >= 0) & (x1 < IMG);
        bool vy0 = (y0 >= 0) & (y0 < IMG), vy1 = (y1 >= 0) & (y1 < IMG);
        int xc0 = min(max(x0, 0), IMG - 1), xc1 = min(max(x1, 0), IMG - 1);
        int yc0 = min(max(y0, 0), IMG - 1), yc1 = min(max(y1, 0), IMG - 1);

        float w00 = (vy0 && vx0) ? wy0 * wx0 : 0.f;
        float w01 = (vy0 && vx1) ? wy0 * wx1 : 0.f;
        float w10 = (vy1 && vx0) ? wy1 * wx0 : 0.f;
        float w11 = (vy1 && vx1) ? wy1 * wx1 : 0.f;

        int o00 = yc0 * IMG + xc0, o01 = yc0 * IMG + xc1;
        int o10 = yc1 * IMG + xc0, o11 = yc1 * IMG + xc1;

        #pragma unroll
        for (int c = 0; c < CH_IN; ++c) {
            float v;
            if (H16) {
                const unsigned short* xp = xh + ((size_t)b * CH_IN + c) * IMG * IMG;
                v = h2f_bits(xp[o00]) * w00 + h2f_bits(xp[o01]) * w01
                  + h2f_bits(xp[o10]) * w10 + h2f_bits(xp[o11]) * w11;
            } else {
                const float* xp = x + ((size_t)b * CH_IN + c) * IMG * IMG;
                v = xp[o00] * w00 + xp[o01] * w01 + xp[o10] * w10 + xp[o11] * w11;
            }
            out[(((size_t)b * CH_IN + c) << 18) + (i << 9) + j] = v;
        }
    }
}

// ---------------------------------------------------------------------------
extern "C" void kernel_launch(void* const* d_in, const int* in_sizes, int n_in,
                              void* d_out, int out_size, void* d_ws, size_t ws_size,
                              hipStream_t stream) {
    const float* x      = (const float*)d_in[0];
    const float* conv_w = (const float*)d_in[1];
    const float* conv_b = (const float*)d_in[2];
    const float* fc_w   = (const float*)d_in[3];
    const float* fc_b   = (const float*)d_in[4];
    float* out = (float*)d_out;

    char* ws = (char*)d_ws;
    unsigned int* counter = (unsigned int*)ws;            // 64 B @ 0
    float* partial = (float*)(ws + 8192);                 // 64 KB
    float* Wf      = (float*)(ws + 139264);               // 2.4 KB
    unsigned short* xh = (unsigned short*)(ws + 147456);  // 48 MB f16 image
    const size_t need = 147456 + (size_t)BATCH * CH_IN * IMG * IMG * 2;
    bool fused = ws_size >= need;

    hipMemsetAsync(counter, 0, 64, stream);               // ticket reset (captured node)
    if (fused) {
        conv_mega_kernel<true><<<dim3(BATCH * TILES_PER_B), dim3(256), 0, stream>>>(
            x, xh, conv_w, conv_b, fc_w, fc_b, partial, Wf, counter);
        tps_sample_kernel<true><<<dim3(4 * 1024), dim3(256), 0, stream>>>(x, xh, Wf, out);
    } else {
        conv_mega_kernel<false><<<dim3(BATCH * TILES_PER_B), dim3(256), 0, stream>>>(
            x, xh, conv_w, conv_b, fc_w, fc_b, partial, Wf, counter);
        tps_sample_kernel<false><<<dim3(4 * 1024), dim3(256), 0, stream>>>(x, xh, Wf, out);
    }
}

// Round 18
// 142.293 us; speedup vs baseline: 1.9422x; 1.9422x over previous
//
#include <hip/hip_runtime.h>
#include <hip/hip_bf16.h>
#include <hip/hip_fp16.h>
#include <math.h>

// Problem constants
#define BATCH 32
#define CH_IN 3
#define CH_OUT 8
#define IMG 512
#define KSZ 7
#define CONV_OUT 506          // 512 - 6
#define KPTS 16
#define TILES_PER_B 64        // 32 row-stripes x 2 col-halves

// Conv MFMA geometry (per tile: 23 rows x 264 f16 px x 3 ch = 36.4 KB)
#define SROWS 23              // 16 out rows + 7 halo (ky padded to 8)
#define ROW_PX 264            // 256 out cols + 6 halo, padded to 8
#define ROW_U4 33             // 16B chunks per row
#define ROW_BYTES 528
#define SMEM_DW (CH_IN * SROWS * (ROW_BYTES / 4))   // 9108 dwords = 36.4 KB
#define NCHUNK (CH_IN * SROWS * ROW_U4)             // 2277

// Sampler: batches per block (4 block-groups x 8 = 32)
#define BPB 8

typedef _Float16 half8_t __attribute__((ext_vector_type(8)));
typedef float f32x4_t __attribute__((ext_vector_type(4)));

__device__ __forceinline__ unsigned short f2h_bits(float f) {
    _Float16 h = (_Float16)f;
    unsigned short u;
    __builtin_memcpy(&u, &h, 2);
    return u;
}
__device__ __forceinline__ float h2f_bits(unsigned short u) {
    _Float16 h;
    __builtin_memcpy(&h, &u, 2);
    return (float)h;
}
__device__ __forceinline__ unsigned int pk2(float a, float b) {
    return (unsigned int)f2h_bits(a) | ((unsigned int)f2h_bits(b) << 16);
}

// ---------------------------------------------------------------------------
// Kernel 0: precompute MFMA A-fragment table Afrag[s][lane] (uint4 = 8 f16).
// ---------------------------------------------------------------------------
__global__ void wprep_kernel(const float* __restrict__ w, uint4* __restrict__ afrag) {
    int idx = blockIdx.x * 256 + threadIdx.x;
    if (idx >= 6 * 64) return;
    int s = idx >> 6, l = idx & 63;
    int m = l & 15;
    int dlt = m >> 3, o = m & 7;
    int oct = s * 4 + (l >> 4);
    int c = oct >> 3, ky = oct & 7;
    unsigned short h[8];
    #pragma unroll
    for (int j = 0; j < 8; ++j) {
        int kx = j - dlt;
        float v = 0.f;
        if (ky < KSZ && kx >= 0 && kx < KSZ)
            v = w[((o * CH_IN + c) * KSZ + ky) * KSZ + kx];
        h[j] = f2h_bits(v);
    }
    uint4 out;
    __builtin_memcpy(&out, h, 16);
    afrag[idx] = out;
}

// ---------------------------------------------------------------------------
// Kernel 1: conv 7x7 + bias + relu + masked spatial sum via MFMA 16x16x32 f16.
// Block = (batch, 16-row stripe, 256-col half): stages once, runs the
// verified 128-col compute loop twice (cc=0,1) reusing the same registers.
// FUSED=true also writes the owned f16-image region (exactly once).
// partial layout: [o][b][tile], tile = stripe*2 + half.
// ---------------------------------------------------------------------------
template <bool FUSED>
__global__ __launch_bounds__(256)
void conv_pool_kernel(const float* __restrict__ x, unsigned short* __restrict__ xh,
                      const uint4* __restrict__ afrag, const float* __restrict__ conv_b,
                      float* __restrict__ partial) {
    __shared__ unsigned int smem[SMEM_DW];
    __shared__ float red[4][8];

    int blk = blockIdx.x;
    int b = blk >> 6;
    int rem0 = blk & 63;
    int stripe = rem0 >> 1;
    int half = rem0 & 1;
    int ybase = stripe * 16;
    int x0 = half * 256;
    int tid = threadIdx.x;

    {
        const float* xb = x + (size_t)b * CH_IN * IMG * IMG;
        unsigned short* xhb = xh + (size_t)b * CH_IN * IMG * IMG;
        for (int idx4 = tid; idx4 < NCHUNK; idx4 += 256) {
            int c = idx4 / (SROWS * ROW_U4);
            int rem = idx4 - c * (SROWS * ROW_U4);
            int r = rem / ROW_U4;
            int u4 = rem - r * ROW_U4;
            int grow = ybase + r;
            int gcol = x0 + (u4 << 3);
            uint4 v = make_uint4(0u, 0u, 0u, 0u);
            if (grow < IMG && gcol < IMG) {   // 8px chunks are fully in or out
                const float* rp = xb + ((size_t)c * IMG + grow) * IMG + gcol;
                float4 f0 = *(const float4*)rp;
                float4 f1 = *(const float4*)(rp + 4);
                v.x = pk2(f0.x, f0.y);
                v.y = pk2(f0.z, f0.w);
                v.z = pk2(f1.x, f1.y);
                v.w = pk2(f1.z, f1.w);
            }
            *(uint4*)((char*)smem + (c * SROWS + r) * ROW_BYTES + (u4 << 4)) = v;
            if (FUSED && r < 16 && u4 < 32)   // owner region: written exactly once
                *(uint4*)(xhb + ((size_t)c * IMG + grow) * IMG + gcol) = v;
        }
    }
    __syncthreads();

    int l = tid & 63, w = tid >> 6;
    int n = l & 15, g = l >> 4;

    uint4 at[6];
    #pragma unroll
    for (int s = 0; s < 6; ++s) at[s] = afrag[s * 64 + l];

    int rowb[6];
    #pragma unroll
    for (int s = 0; s < 6; ++s) {
        int oct = s * 4 + g;
        int c = oct >> 3, ky = oct & 7;
        rowb[s] = (c * SROWS + n + ky) * ROW_BYTES + w * 64;
    }

    float bias_[4];
    {
        int ob = (g & 1) * 4;
        #pragma unroll
        for (int r2 = 0; r2 < 4; ++r2) bias_[r2] = conv_b[ob + r2];
    }
    bool rowok = (ybase + n) < CONV_OUT;
    int dlt = g >> 1;
    float sums[4] = {0.f, 0.f, 0.f, 0.f};
    const char* sb = (const char*)smem;

    #pragma unroll
    for (int cc = 0; cc < 2; ++cc) {          // two 128-col chunks, same registers
        int off = cc * 256;                   // byte offset: 128 px * 2 B
        #pragma unroll
        for (int u = 0; u < 4; ++u) {
            f32x4_t acc[4];
            #pragma unroll
            for (int d = 0; d < 4; ++d) acc[d] = (f32x4_t){0.f, 0.f, 0.f, 0.f};

            #pragma unroll
            for (int s = 0; s < 6; ++s) {
                uint4 lo = *(const uint4*)(sb + rowb[s] + off + (u << 4));
                uint4 hi = *(const uint4*)(sb + rowb[s] + off + (u << 4) + 16);
                unsigned int eu[8] = {lo.x, lo.y, lo.z, lo.w, hi.x, hi.y, hi.z, hi.w};
                half8_t a;
                __builtin_memcpy(&a, &at[s], 16);
                #pragma unroll
                for (int d = 0; d < 4; ++d) {
                    uint4 bu = make_uint4(eu[d], eu[d + 1], eu[d + 2], eu[d + 3]);
                    half8_t bf;
                    __builtin_memcpy(&bf, &bu, 16);
                    acc[d] = __builtin_amdgcn_mfma_f32_16x16x32_f16(a, bf, acc[d], 0, 0, 0);
                }
            }

            #pragma unroll
            for (int d = 0; d < 4; ++d) {
                int col = x0 + cc * 128 + 32 * w + 8 * u + 2 * d + dlt;
                bool colok = col < CONV_OUT;
                #pragma unroll
                for (int r2 = 0; r2 < 4; ++r2) {
                    float v = acc[d][r2] + bias_[r2];
                    v = v > 0.f ? v : 0.f;
                    sums[r2] += (rowok && colok) ? v : 0.f;
                }
            }
        }
    }

    #pragma unroll
    for (int r2 = 0; r2 < 4; ++r2) {
        sums[r2] += __shfl_xor(sums[r2], 1, 64);
        sums[r2] += __shfl_xor(sums[r2], 2, 64);
        sums[r2] += __shfl_xor(sums[r2], 4, 64);
        sums[r2] += __shfl_xor(sums[r2], 8, 64);
        sums[r2] += __shfl_xor(sums[r2], 32, 64);
    }
    if (l == 0) {
        #pragma unroll
        for (int r2 = 0; r2 < 4; ++r2) red[w][r2] = sums[r2];
    }
    if (l == 16) {
        #pragma unroll
        for (int r2 = 0; r2 < 4; ++r2) red[w][4 + r2] = sums[r2];
    }
    __syncthreads();
    if (tid < CH_OUT) {
        float s = red[0][tid] + red[1][tid] + red[2][tid] + red[3][tid];
        partial[tid * (BATCH * TILES_PER_B) + b * TILES_PER_B + stripe * 2 + half] = s;
    }
}

// ---------------------------------------------------------------------------
// Kernel 2: pooled mean (ILP float4 reduce) + FC -> pred, TPS system,
// pivoted LU solve (double), emit Wmat as float [32][19][2]. 64 threads.
// ---------------------------------------------------------------------------
__device__ __forceinline__ double ctrl_lin(int i) { return -1.0 + (2.0 / 3.0) * i; }

__global__ void solve_kernel(const float* __restrict__ partial,
                             const float* __restrict__ fc_w,
                             const float* __restrict__ fc_b,
                             float* __restrict__ Wf) {
    __shared__ double L[19][19];
    __shared__ double Ys[19][64];
    __shared__ double piv_fac[19];
    __shared__ int piv_idx;
    __shared__ float pooledS[BATCH][CH_OUT];

    int t = threadIdx.x;

    for (int p = t; p < BATCH * CH_OUT; p += 64) {
        int b = p >> 3, o = p & 7;
        const float4* pp = (const float4*)(partial + o * (BATCH * TILES_PER_B) + b * TILES_PER_B);
        double a0 = 0.0, a1 = 0.0, a2 = 0.0, a3 = 0.0;
        #pragma unroll
        for (int gq = 0; gq < TILES_PER_B / 4; ++gq) {
            float4 v = pp[gq];
            a0 += (double)v.x; a1 += (double)v.y;
            a2 += (double)v.z; a3 += (double)v.w;
        }
        pooledS[b][o] = (float)(((a0 + a1) + (a2 + a3)) / ((double)CONV_OUT * (double)CONV_OUT));
    }
    __syncthreads();

    {
        int b = t >> 1, c = t & 1;
        for (int k = 0; k < KPTS; ++k) {
            int j = k * 2 + c;
            double s = (double)fc_b[j];
            for (int o = 0; o < CH_OUT; ++o)
                s += (double)pooledS[b][o] * (double)fc_w[j * CH_OUT + o];
            Ys[k][t] = s;
        }
        for (int k = KPTS; k < 19; ++k) Ys[k][t] = 0.0;
    }

    for (int p = t; p < 19 * 19; p += 64) {
        int r = p / 19, cc = p % 19;
        double v;
        if (r < KPTS && cc < KPTS) {
            double dx = ctrl_lin(r & 3) - ctrl_lin(cc & 3);
            double dy = ctrl_lin(r >> 2) - ctrl_lin(cc >> 2);
            double d2 = dx * dx + dy * dy;
            v = d2 * log(d2 + 1e-6);
        } else if (r < KPTS) {
            v = (cc == KPTS) ? 1.0 : (cc == KPTS + 1 ? ctrl_lin(r & 3) : ctrl_lin(r >> 2));
        } else if (cc < KPTS) {
            v = (r == KPTS) ? 1.0 : (r == KPTS + 1 ? ctrl_lin(cc & 3) : ctrl_lin(cc >> 2));
        } else v = 0.0;
        L[r][cc] = v;
    }
    __syncthreads();

    for (int k = 0; k < 19; ++k) {
        if (t == 0) {
            int pi = k; double mx = fabs(L[k][k]);
            for (int i = k + 1; i < 19; ++i) {
                double a = fabs(L[i][k]);
                if (a > mx) { mx = a; pi = i; }
            }
            piv_idx = pi;
        }
        __syncthreads();
        int pi = piv_idx;
        if (pi != k) {
            if (t < 19) { double tmp = L[k][t]; L[k][t] = L[pi][t]; L[pi][t] = tmp; }
            { double tmp = Ys[k][t]; Ys[k][t] = Ys[pi][t]; Ys[pi][t] = tmp; }
        }
        __syncthreads();
        if (t > k && t < 19) piv_fac[t] = L[t][k] / L[k][k];
        __syncthreads();
        if (t > k && t < 19) {
            double lkj = L[k][t];
            for (int i = k + 1; i < 19; ++i) L[i][t] -= piv_fac[i] * lkj;
        }
        {
            double ykt = Ys[k][t];
            for (int i = k + 1; i < 19; ++i) Ys[i][t] -= piv_fac[i] * ykt;
        }
        __syncthreads();
    }

    for (int k = 18; k >= 0; --k) {
        double s = Ys[k][t];
        for (int j = k + 1; j < 19; ++j) s -= L[k][j] * Ys[j][t];
        Ys[k][t] = s / L[k][k];
    }

    {
        int b = t >> 1, c = t & 1;
        for (int k = 0; k < 19; ++k)
            Wf[(b * 19 + k) * 2 + c] = (float)Ys[k][t];
    }
}

// ---------------------------------------------------------------------------
// Kernel 3: fused TPS grid + bilinear sample, batch-amortized basis.
// ---------------------------------------------------------------------------
template <bool H16>
__global__ __launch_bounds__(256)
void tps_sample_kernel(const float* __restrict__ x, const unsigned short* __restrict__ xh,
                       const float* __restrict__ Wf, float* __restrict__ out) {
    int blk = blockIdx.x;
    int bgrp = blk >> 10;                     // 0..3 -> batches [8*bgrp, 8*bgrp+8)
    int pix = ((blk & 1023) << 8) | threadIdx.x;
    int i = pix >> 9, j = pix & 511;

    float gx = -1.f + (2.f / 511.f) * (float)j;
    float gy = -1.f + (2.f / 511.f) * (float)i;

    float U[KPTS];
    #pragma unroll
    for (int k = 0; k < KPTS; ++k) {
        float sx = -1.f + (2.f / 3.f) * (float)(k & 3);
        float sy = -1.f + (2.f / 3.f) * (float)(k >> 2);
        float dx = gx - sx, dy = gy - sy;
        float d2 = dx * dx + dy * dy;
        U[k] = d2 * (0.69314718055994531f * __log2f(d2 + 1e-6f));
    }

    for (int b = bgrp * BPB; b < bgrp * BPB + BPB; ++b) {
        const float* Wb = Wf + b * 38;        // wave-uniform -> s_load

        float mx = Wb[32] + gx * Wb[34] + gy * Wb[36];
        float my = Wb[33] + gx * Wb[35] + gy * Wb[37];
        #pragma unroll
        for (int k = 0; k < KPTS; ++k) {
            mx += U[k] * Wb[2 * k];
            my += U[k] * Wb[2 * k + 1];
        }

        float ix = (mx + 1.f) * 256.f - 0.5f;
        float iy = (my + 1.f) * 256.f - 0.5f;
        float x0f = floorf(ix), y0f = floorf(iy);
        int x0 = (int)x0f, y0 = (int)y0f;
        int x1 = x0 + 1, y1 = y0 + 1;
        float wx1 = ix - x0f, wy1 = iy - y0f;
        float wx0 = 1.f - wx1, wy0 = 1.f - wy1;

        bool vx0 = (x0 >= 0) & (x0 < IMG), vx1 = (x1 >= 0) & (x1 < IMG);
        bool vy0 = (y0 >= 0) & (y0 < IMG), vy1 = (y1 >= 0) & (y1 < IMG);
        int xc0 = min(max(x0, 0), IMG - 1), xc1 = min(max(x1, 0), IMG - 1);
        int yc0 = min(max(y0, 0), IMG - 1), yc1 = min(max(y1, 0), IMG - 1);

        float w00 = (vy0 && vx0) ? wy0 * wx0 : 0.f;
        float w01 = (vy0 && vx1) ? wy0 * wx1 : 0.f;
        float w10 = (vy1 && vx0) ? wy1 * wx0 : 0.f;
        float w11 = (vy1 && vx1) ? wy1 * wx1 : 0.f;

        int o00 = yc0 * IMG + xc0, o01 = yc0 * IMG + xc1;
        int o10 = yc1 * IMG + xc0, o11 = yc1 * IMG + xc1;

        #pragma unroll
        for (int c = 0; c < CH_IN; ++c) {
            float v;
            if (H16) {
                const unsigned short* xp = xh + ((size_t)b * CH_IN + c) * IMG * IMG;
                v = h2f_bits(xp[o00]) * w00 + h2f_bits(xp[o01]) * w01
                  + h2f_bits(xp[o10]) * w10 + h2f_bits(xp[o11]) * w11;
            } else {
                const float* xp = x + ((size_t)b * CH_IN + c) * IMG * IMG;
                v = xp[o00] * w00 + xp[o01] * w01 + xp[o10] * w10 + xp[o11] * w11;
            }
            out[(((size_t)b * CH_IN + c) << 18) + (i << 9) + j] = v;
        }
    }
}

// ---------------------------------------------------------------------------
extern "C" void kernel_launch(void* const* d_in, const int* in_sizes, int n_in,
                              void* d_out, int out_size, void* d_ws, size_t ws_size,
                              hipStream_t stream) {
    const float* x      = (const float*)d_in[0];
    const float* conv_w = (const float*)d_in[1];
    const float* conv_b = (const float*)d_in[2];
    const float* fc_w   = (const float*)d_in[3];
    const float* fc_b   = (const float*)d_in[4];
    float* out = (float*)d_out;

    char* ws = (char*)d_ws;
    uint4* afrag   = (uint4*)ws;                          // 6 KB @ 0
    float* partial = (float*)(ws + 8192);                 // 64 KB
    float* Wf      = (float*)(ws + 139264);               // 2.4 KB
    unsigned short* xh = (unsigned short*)(ws + 147456);  // 48 MB f16 image
    const size_t need = 147456 + (size_t)BATCH * CH_IN * IMG * IMG * 2;
    bool fused = ws_size >= need;

    wprep_kernel<<<dim3(2), dim3(256), 0, stream>>>(conv_w, afrag);
    if (fused) {
        conv_pool_kernel<true><<<dim3(BATCH * TILES_PER_B), dim3(256), 0, stream>>>(
            x, xh, afrag, conv_b, partial);
    } else {
        conv_pool_kernel<false><<<dim3(BATCH * TILES_PER_B), dim3(256), 0, stream>>>(
            x, xh, afrag, conv_b, partial);
    }
    solve_kernel<<<dim3(1), dim3(64), 0, stream>>>(partial, fc_w, fc_b, Wf);
    if (fused) {
        tps_sample_kernel<true><<<dim3(4 * 1024), dim3(256), 0, stream>>>(x, xh, Wf, out);
    } else {
        tps_sample_kernel<false><<<dim3(4 * 1024), dim3(256), 0, stream>>>(x, xh, Wf, out);
    }
}

// Round 19
// 140.169 us; speedup vs baseline: 1.9717x; 1.0152x over previous
//
#include <hip/hip_runtime.h>
#include <hip/hip_bf16.h>
#include <hip/hip_fp16.h>
#include <math.h>

// Problem constants
#define BATCH 32
#define CH_IN 3
#define CH_OUT 8
#define IMG 512
#define KSZ 7
#define CONV_OUT 506          // 512 - 6
#define KPTS 16
#define TILES_PER_B 64        // 32 row-stripes x 2 col-halves

// Conv MFMA geometry (per tile: 23 rows x 264 f16 px x 3 ch = 36.4 KB)
#define SROWS 23              // 16 out rows + 7 halo (ky padded to 8)
#define ROW_U4 33             // 16B chunks per row
#define ROW_BYTES 528
#define SMEM_DW (CH_IN * SROWS * (ROW_BYTES / 4))   // 9108 dwords = 36.4 KB
#define NCHUNK (CH_IN * SROWS * ROW_U4)             // 2277

// Sampler: batches per block (4 block-groups x 8 = 32)
#define BPB 8

typedef _Float16 half8_t __attribute__((ext_vector_type(8)));
typedef float f32x4_t __attribute__((ext_vector_type(4)));

__device__ __forceinline__ unsigned short f2h_bits(float f) {
    _Float16 h = (_Float16)f;
    unsigned short u;
    __builtin_memcpy(&u, &h, 2);
    return u;
}
__device__ __forceinline__ float h2f_bits(unsigned short u) {
    _Float16 h;
    __builtin_memcpy(&h, &u, 2);
    return (float)h;
}
__device__ __forceinline__ unsigned int pk2(float a, float b) {
    return (unsigned int)f2h_bits(a) | ((unsigned int)f2h_bits(b) << 16);
}

// ---------------------------------------------------------------------------
// Kernel 1: conv 7x7 + bias + relu + masked spatial sum via MFMA 16x16x32 f16.
// A-fragment table built cooperatively in LDS (no separate wprep launch; no
// fence/ticket — that was R17's regression). Block = (batch, 16-row stripe,
// 256-col half): stages once, runs the verified 128-col compute loop twice.
// FUSED=true also writes the owned f16-image region (exactly once).
// partial layout: [o][b][tile], tile = stripe*2 + half.
// ---------------------------------------------------------------------------
template <bool FUSED>
__global__ __launch_bounds__(256)
void conv_pool_kernel(const float* __restrict__ x, unsigned short* __restrict__ xh,
                      const float* __restrict__ conv_w, const float* __restrict__ conv_b,
                      float* __restrict__ partial) {
    __shared__ __attribute__((aligned(16))) unsigned int smem[SMEM_DW];
    __shared__ uint4 afrag_s[6 * 64];          // 6 KB
    __shared__ float red[4][8];

    int blk = blockIdx.x;
    int b = blk >> 6;
    int rem0 = blk & 63;
    int stripe = rem0 >> 1;
    int half = rem0 & 1;
    int ybase = stripe * 16;
    int x0 = half * 256;
    int tid = threadIdx.x;

    // ---- cooperative A-fragment build (parallel, L2-hot conv_w) ----
    for (int idx = tid; idx < 6 * 64; idx += 256) {
        int s = idx >> 6, l = idx & 63;
        int m = l & 15;
        int dlt = m >> 3, o = m & 7;
        int oct = s * 4 + (l >> 4);
        int c = oct >> 3, ky = oct & 7;
        unsigned short h[8];
        #pragma unroll
        for (int j = 0; j < 8; ++j) {
            int kx = j - dlt;
            float v = 0.f;
            if (ky < KSZ && kx >= 0 && kx < KSZ)
                v = conv_w[((o * CH_IN + c) * KSZ + ky) * KSZ + kx];
            h[j] = f2h_bits(v);
        }
        uint4 outv;
        __builtin_memcpy(&outv, h, 16);
        afrag_s[idx] = outv;
    }

    // ---- staging: f32 -> f16 pack -> LDS (+ owned xh region) ----
    {
        const float* xb = x + (size_t)b * CH_IN * IMG * IMG;
        unsigned short* xhb = xh + (size_t)b * CH_IN * IMG * IMG;
        for (int idx4 = tid; idx4 < NCHUNK; idx4 += 256) {
            int c = idx4 / (SROWS * ROW_U4);
            int rem = idx4 - c * (SROWS * ROW_U4);
            int r = rem / ROW_U4;
            int u4 = rem - r * ROW_U4;
            int grow = ybase + r;
            int gcol = x0 + (u4 << 3);
            uint4 v = make_uint4(0u, 0u, 0u, 0u);
            if (grow < IMG && gcol < IMG) {   // 8px chunks are fully in or out
                const float* rp = xb + ((size_t)c * IMG + grow) * IMG + gcol;
                float4 f0 = *(const float4*)rp;
                float4 f1 = *(const float4*)(rp + 4);
                v.x = pk2(f0.x, f0.y);
                v.y = pk2(f0.z, f0.w);
                v.z = pk2(f1.x, f1.y);
                v.w = pk2(f1.z, f1.w);
            }
            *(uint4*)((char*)smem + (c * SROWS + r) * ROW_BYTES + (u4 << 4)) = v;
            if (FUSED && r < 16 && u4 < 32)   // owner region: written exactly once
                *(uint4*)(xhb + ((size_t)c * IMG + grow) * IMG + gcol) = v;
        }
    }
    __syncthreads();

    int l = tid & 63, w = tid >> 6;
    int n = l & 15, g = l >> 4;

    uint4 at[6];
    #pragma unroll
    for (int s = 0; s < 6; ++s) at[s] = afrag_s[s * 64 + l];

    int rowb[6];
    #pragma unroll
    for (int s = 0; s < 6; ++s) {
        int oct = s * 4 + g;
        int c = oct >> 3, ky = oct & 7;
        rowb[s] = (c * SROWS + n + ky) * ROW_BYTES + w * 64;
    }

    float bias_[4];
    {
        int ob = (g & 1) * 4;
        #pragma unroll
        for (int r2 = 0; r2 < 4; ++r2) bias_[r2] = conv_b[ob + r2];
    }
    bool rowok = (ybase + n) < CONV_OUT;
    int dlt = g >> 1;
    float sums[4] = {0.f, 0.f, 0.f, 0.f};
    const char* sb = (const char*)smem;

    #pragma unroll
    for (int cc = 0; cc < 2; ++cc) {          // two 128-col chunks, same registers
        int off = cc * 256;                   // byte offset: 128 px * 2 B
        #pragma unroll
        for (int u = 0; u < 4; ++u) {
            f32x4_t acc[4];
            #pragma unroll
            for (int d = 0; d < 4; ++d) acc[d] = (f32x4_t){0.f, 0.f, 0.f, 0.f};

            #pragma unroll
            for (int s = 0; s < 6; ++s) {
                uint4 lo = *(const uint4*)(sb + rowb[s] + off + (u << 4));
                uint4 hi = *(const uint4*)(sb + rowb[s] + off + (u << 4) + 16);
                unsigned int eu[8] = {lo.x, lo.y, lo.z, lo.w, hi.x, hi.y, hi.z, hi.w};
                half8_t a;
                __builtin_memcpy(&a, &at[s], 16);
                #pragma unroll
                for (int d = 0; d < 4; ++d) {
                    uint4 bu = make_uint4(eu[d], eu[d + 1], eu[d + 2], eu[d + 3]);
                    half8_t bf;
                    __builtin_memcpy(&bf, &bu, 16);
                    acc[d] = __builtin_amdgcn_mfma_f32_16x16x32_f16(a, bf, acc[d], 0, 0, 0);
                }
            }

            #pragma unroll
            for (int d = 0; d < 4; ++d) {
                int col = x0 + cc * 128 + 32 * w + 8 * u + 2 * d + dlt;
                bool colok = col < CONV_OUT;
                #pragma unroll
                for (int r2 = 0; r2 < 4; ++r2) {
                    float v = acc[d][r2] + bias_[r2];
                    v = v > 0.f ? v : 0.f;
                    sums[r2] += (rowok && colok) ? v : 0.f;
                }
            }
        }
    }

    #pragma unroll
    for (int r2 = 0; r2 < 4; ++r2) {
        sums[r2] += __shfl_xor(sums[r2], 1, 64);
        sums[r2] += __shfl_xor(sums[r2], 2, 64);
        sums[r2] += __shfl_xor(sums[r2], 4, 64);
        sums[r2] += __shfl_xor(sums[r2], 8, 64);
        sums[r2] += __shfl_xor(sums[r2], 32, 64);
    }
    if (l == 0) {
        #pragma unroll
        for (int r2 = 0; r2 < 4; ++r2) red[w][r2] = sums[r2];
    }
    if (l == 16) {
        #pragma unroll
        for (int r2 = 0; r2 < 4; ++r2) red[w][4 + r2] = sums[r2];
    }
    __syncthreads();
    if (tid < CH_OUT) {
        float s = red[0][tid] + red[1][tid] + red[2][tid] + red[3][tid];
        partial[tid * (BATCH * TILES_PER_B) + b * TILES_PER_B + stripe * 2 + half] = s;
    }
}

// ---------------------------------------------------------------------------
// Kernel 2: pooled mean (ILP float4 reduce) + FC -> pred, TPS system,
// pivoted LU solve (double), emit Wmat as float [32][19][2]. 64 threads.
// ---------------------------------------------------------------------------
__device__ __forceinline__ double ctrl_lin(int i) { return -1.0 + (2.0 / 3.0) * i; }

__global__ void solve_kernel(const float* __restrict__ partial,
                             const float* __restrict__ fc_w,
                             const float* __restrict__ fc_b,
                             float* __restrict__ Wf) {
    __shared__ double L[19][19];
    __shared__ double Ys[19][64];
    __shared__ double piv_fac[19];
    __shared__ int piv_idx;
    __shared__ float pooledS[BATCH][CH_OUT];

    int t = threadIdx.x;

    for (int p = t; p < BATCH * CH_OUT; p += 64) {
        int b = p >> 3, o = p & 7;
        const float4* pp = (const float4*)(partial + o * (BATCH * TILES_PER_B) + b * TILES_PER_B);
        double a0 = 0.0, a1 = 0.0, a2 = 0.0, a3 = 0.0;
        #pragma unroll
        for (int gq = 0; gq < TILES_PER_B / 4; ++gq) {
            float4 v = pp[gq];
            a0 += (double)v.x; a1 += (double)v.y;
            a2 += (double)v.z; a3 += (double)v.w;
        }
        pooledS[b][o] = (float)(((a0 + a1) + (a2 + a3)) / ((double)CONV_OUT * (double)CONV_OUT));
    }
    __syncthreads();

    {
        int b = t >> 1, c = t & 1;
        for (int k = 0; k < KPTS; ++k) {
            int j = k * 2 + c;
            double s = (double)fc_b[j];
            for (int o = 0; o < CH_OUT; ++o)
                s += (double)pooledS[b][o] * (double)fc_w[j * CH_OUT + o];
            Ys[k][t] = s;
        }
        for (int k = KPTS; k < 19; ++k) Ys[k][t] = 0.0;
    }

    for (int p = t; p < 19 * 19; p += 64) {
        int r = p / 19, cc = p % 19;
        double v;
        if (r < KPTS && cc < KPTS) {
            double dx = ctrl_lin(r & 3) - ctrl_lin(cc & 3);
            double dy = ctrl_lin(r >> 2) - ctrl_lin(cc >> 2);
            double d2 = dx * dx + dy * dy;
            v = d2 * log(d2 + 1e-6);
        } else if (r < KPTS) {
            v = (cc == KPTS) ? 1.0 : (cc == KPTS + 1 ? ctrl_lin(r & 3) : ctrl_lin(r >> 2));
        } else if (cc < KPTS) {
            v = (r == KPTS) ? 1.0 : (r == KPTS + 1 ? ctrl_lin(cc & 3) : ctrl_lin(cc >> 2));
        } else v = 0.0;
        L[r][cc] = v;
    }
    __syncthreads();

    for (int k = 0; k < 19; ++k) {
        if (t == 0) {
            int pi = k; double mx = fabs(L[k][k]);
            for (int i = k + 1; i < 19; ++i) {
                double a = fabs(L[i][k]);
                if (a > mx) { mx = a; pi = i; }
            }
            piv_idx = pi;
        }
        __syncthreads();
        int pi = piv_idx;
        if (pi != k) {
            if (t < 19) { double tmp = L[k][t]; L[k][t] = L[pi][t]; L[pi][t] = tmp; }
            { double tmp = Ys[k][t]; Ys[k][t] = Ys[pi][t]; Ys[pi][t] = tmp; }
        }
        __syncthreads();
        if (t > k && t < 19) piv_fac[t] = L[t][k] / L[k][k];
        __syncthreads();
        if (t > k && t < 19) {
            double lkj = L[k][t];
            for (int i = k + 1; i < 19; ++i) L[i][t] -= piv_fac[i] * lkj;
        }
        {
            double ykt = Ys[k][t];
            for (int i = k + 1; i < 19; ++i) Ys[i][t] -= piv_fac[i] * ykt;
        }
        __syncthreads();
    }

    for (int k = 18; k >= 0; --k) {
        double s = Ys[k][t];
        for (int j = k + 1; j < 19; ++j) s -= L[k][j] * Ys[j][t];
        Ys[k][t] = s / L[k][k];
    }

    {
        int b = t >> 1, c = t & 1;
        for (int k = 0; k < 19; ++k)
            Wf[(b * 19 + k) * 2 + c] = (float)Ys[k][t];
    }
}

// ---------------------------------------------------------------------------
// Kernel 3: fused TPS grid + bilinear sample, batch-amortized basis.
// ---------------------------------------------------------------------------
template <bool H16>
__global__ __launch_bounds__(256)
void tps_sample_kernel(const float* __restrict__ x, const unsigned short* __restrict__ xh,
                       const float* __restrict__ Wf, float* __restrict__ out) {
    int blk = blockIdx.x;
    int bgrp = blk >> 10;                     // 0..3 -> batches [8*bgrp, 8*bgrp+8)
    int pix = ((blk & 1023) << 8) | threadIdx.x;
    int i = pix >> 9, j = pix & 511;

    float gx = -1.f + (2.f / 511.f) * (float)j;
    float gy = -1.f + (2.f / 511.f) * (float)i;

    float U[KPTS];
    #pragma unroll
    for (int k = 0; k < KPTS; ++k) {
        float sx = -1.f + (2.f / 3.f) * (float)(k & 3);
        float sy = -1.f + (2.f / 3.f) * (float)(k >> 2);
        float dx = gx - sx, dy = gy - sy;
        float d2 = dx * dx + dy * dy;
        U[k] = d2 * (0.69314718055994531f * __log2f(d2 + 1e-6f));
    }

    for (int b = bgrp * BPB; b < bgrp * BPB + BPB; ++b) {
        const float* Wb = Wf + b * 38;        // wave-uniform -> s_load

        float mx = Wb[32] + gx * Wb[34] + gy * Wb[36];
        float my = Wb[33] + gx * Wb[35] + gy * Wb[37];
        #pragma unroll
        for (int k = 0; k < KPTS; ++k) {
            mx += U[k] * Wb[2 * k];
            my += U[k] * Wb[2 * k + 1];
        }

        float ix = (mx + 1.f) * 256.f - 0.5f;
        float iy = (my + 1.f) * 256.f - 0.5f;
        float x0f = floorf(ix), y0f = floorf(iy);
        int x0 = (int)x0f, y0 = (int)y0f;
        int x1 = x0 + 1, y1 = y0 + 1;
        float wx1 = ix - x0f, wy1 = iy - y0f;
        float wx0 = 1.f - wx1, wy0 = 1.f - wy1;

        bool vx0 = (x0 >= 0) & (x0 < IMG), vx1 = (x1 >= 0) & (x1 < IMG);
        bool vy0 = (y0 >= 0) & (y0 < IMG), vy1 = (y1 >= 0) & (y1 < IMG);
        int xc0 = min(max(x0, 0), IMG - 1), xc1 = min(max(x1, 0), IMG - 1);
        int yc0 = min(max(y0, 0), IMG - 1), yc1 = min(max(y1, 0), IMG - 1);

        float w00 = (vy0 && vx0) ? wy0 * wx0 : 0.f;
        float w01 = (vy0 && vx1) ? wy0 * wx1 : 0.f;
        float w10 = (vy1 && vx0) ? wy1 * wx0 : 0.f;
        float w11 = (vy1 && vx1) ? wy1 * wx1 : 0.f;

        int o00 = yc0 * IMG + xc0, o01 = yc0 * IMG + xc1;
        int o10 = yc1 * IMG + xc0, o11 = yc1 * IMG + xc1;

        #pragma unroll
        for (int c = 0; c < CH_IN; ++c) {
            float v;
            if (H16) {
                const unsigned short* xp = xh + ((size_t)b * CH_IN + c) * IMG * IMG;
                v = h2f_bits(xp[o00]) * w00 + h2f_bits(xp[o01]) * w01
                  + h2f_bits(xp[o10]) * w10 + h2f_bits(xp[o11]) * w11;
            } else {
                const float* xp = x + ((size_t)b * CH_IN + c) * IMG * IMG;
                v = xp[o00] * w00 + xp[o01] * w01 + xp[o10] * w10 + xp[o11] * w11;
            }
            out[(((size_t)b * CH_IN + c) << 18) + (i << 9) + j] = v;
        }
    }
}

// ---------------------------------------------------------------------------
extern "C" void kernel_launch(void* const* d_in, const int* in_sizes, int n_in,
                              void* d_out, int out_size, void* d_ws, size_t ws_size,
                              hipStream_t stream) {
    const float* x      = (const float*)d_in[0];
    const float* conv_w = (const float*)d_in[1];
    const float* conv_b = (const float*)d_in[2];
    const float* fc_w   = (const float*)d_in[3];
    const float* fc_b   = (const float*)d_in[4];
    float* out = (float*)d_out;

    char* ws = (char*)d_ws;
    float* partial = (float*)(ws + 8192);                 // 64 KB
    float* Wf      = (float*)(ws + 139264);               // 2.4 KB
    unsigned short* xh = (unsigned short*)(ws + 147456);  // 48 MB f16 image
    const size_t need = 147456 + (size_t)BATCH * CH_IN * IMG * IMG * 2;
    bool fused = ws_size >= need;

    if (fused) {
        conv_pool_kernel<true><<<dim3(BATCH * TILES_PER_B), dim3(256), 0, stream>>>(
            x, xh, conv_w, conv_b, partial);
    } else {
        conv_pool_kernel<false><<<dim3(BATCH * TILES_PER_B), dim3(256), 0, stream>>>(
            x, xh, conv_w, conv_b, partial);
    }
    solve_kernel<<<dim3(1), dim3(64), 0, stream>>>(partial, fc_w, fc_b, Wf);
    if (fused) {
        tps_sample_kernel<true><<<dim3(4 * 1024), dim3(256), 0, stream>>>(x, xh, Wf, out);
    } else {
        tps_sample_kernel<false><<<dim3(4 * 1024), dim3(256), 0, stream>>>(x, xh, Wf, out);
    }
}